// Round 1
// baseline (953.241 us; speedup 1.0000x reference)
//
#include <hip/hip_runtime.h>
#include <hip/hip_bf16.h>
#include <math.h>

#define NN 20000
#define INDIM 1536
#define HID 256
#define NE 320000
#define NEDGE (NE + NN)
#define EPSV 1e-5f
#define NEG 0.2f

// ----------------------------------------------------------------------------
// Generic fp32 tiled GEMM: C = A[M,K] @ B[K,Ncols] + bias (+ optional exact GELU)
// 64x64 tile, 256 threads, 4x4 micro-tile per thread, K chunk = 16.
// ----------------------------------------------------------------------------
__global__ __launch_bounds__(256) void gemm_bias_kernel(
    const float* __restrict__ A, const float* __restrict__ B,
    const float* __restrict__ bias, float* __restrict__ C,
    int M, int K, int Ncols, int do_gelu)
{
  __shared__ __align__(16) float As[16][68];
  __shared__ __align__(16) float Bs[16][64];
  int tid = threadIdx.x;
  int tx = tid & 15, ty = tid >> 4;
  int c0 = blockIdx.x * 64;
  int r0 = blockIdx.y * 64;

  float acc[4][4];
#pragma unroll
  for (int i = 0; i < 4; i++)
#pragma unroll
    for (int j = 0; j < 4; j++) acc[i][j] = 0.f;

  int a_r = r0 + (tid >> 2);
  int a_k = (tid & 3) << 2;
  int b_k = tid >> 4;
  int b_c = c0 + ((tid & 15) << 2);

  for (int k0 = 0; k0 < K; k0 += 16) {
    float4 av = make_float4(0.f, 0.f, 0.f, 0.f);
    if (a_r < M) av = *(const float4*)(A + (size_t)a_r * K + (k0 + a_k));
    float4 bv = *(const float4*)(B + (size_t)(k0 + b_k) * Ncols + b_c);
    As[a_k + 0][tid >> 2] = av.x;
    As[a_k + 1][tid >> 2] = av.y;
    As[a_k + 2][tid >> 2] = av.z;
    As[a_k + 3][tid >> 2] = av.w;
    *(float4*)&Bs[b_k][(tid & 15) << 2] = bv;
    __syncthreads();
#pragma unroll
    for (int kk = 0; kk < 16; kk++) {
      float4 a = *(const float4*)&As[kk][ty << 2];
      float4 b = *(const float4*)&Bs[kk][tx << 2];
      acc[0][0] += a.x * b.x; acc[0][1] += a.x * b.y; acc[0][2] += a.x * b.z; acc[0][3] += a.x * b.w;
      acc[1][0] += a.y * b.x; acc[1][1] += a.y * b.y; acc[1][2] += a.y * b.z; acc[1][3] += a.y * b.w;
      acc[2][0] += a.z * b.x; acc[2][1] += a.z * b.y; acc[2][2] += a.z * b.z; acc[2][3] += a.z * b.w;
      acc[3][0] += a.w * b.x; acc[3][1] += a.w * b.y; acc[3][2] += a.w * b.z; acc[3][3] += a.w * b.w;
    }
    __syncthreads();
  }

  float4 bb = *(const float4*)(bias + c0 + (tx << 2));
#pragma unroll
  for (int i = 0; i < 4; i++) {
    int row = r0 + (ty << 2) + i;
    if (row < M) {
      float4 o;
      o.x = acc[i][0] + bb.x;
      o.y = acc[i][1] + bb.y;
      o.z = acc[i][2] + bb.z;
      o.w = acc[i][3] + bb.w;
      if (do_gelu) {
        o.x = 0.5f * o.x * (1.f + erff(o.x * 0.70710678118654752f));
        o.y = 0.5f * o.y * (1.f + erff(o.y * 0.70710678118654752f));
        o.z = 0.5f * o.z * (1.f + erff(o.z * 0.70710678118654752f));
        o.w = 0.5f * o.w * (1.f + erff(o.w * 0.70710678118654752f));
      }
      *(float4*)(C + (size_t)row * Ncols + c0 + (tx << 2)) = o;
    }
  }
}

// ----------------------------------------------------------------------------
// LayerNorm over rows of 256. One wave per row, 4 rows per 256-thread block.
// ----------------------------------------------------------------------------
__global__ __launch_bounds__(256) void ln4_kernel(
    const float* __restrict__ in, const float* __restrict__ g,
    const float* __restrict__ b, float* __restrict__ out, int n)
{
  int wave = threadIdx.x >> 6, lane = threadIdx.x & 63;
  int row = blockIdx.x * 4 + wave;
  if (row >= n) return;
  int c = lane << 2;
  float4 v = *(const float4*)(in + (size_t)row * HID + c);
  float s1 = v.x + v.y + v.z + v.w;
  float s2 = v.x * v.x + v.y * v.y + v.z * v.z + v.w * v.w;
#pragma unroll
  for (int m = 1; m < 64; m <<= 1) {
    s1 += __shfl_xor(s1, m, 64);
    s2 += __shfl_xor(s2, m, 64);
  }
  float mu = s1 * (1.f / 256.f);
  float var = s2 * (1.f / 256.f) - mu * mu;
  float rstd = rsqrtf(var + EPSV);
  float4 gv = *(const float4*)(g + c);
  float4 bv = *(const float4*)(b + c);
  float4 o;
  o.x = (v.x - mu) * rstd * gv.x + bv.x;
  o.y = (v.y - mu) * rstd * gv.y + bv.y;
  o.z = (v.z - mu) * rstd * gv.z + bv.z;
  o.w = (v.w - mu) * rstd * gv.w + bv.w;
  *(float4*)(out + (size_t)row * HID + c) = o;
}

// ----------------------------------------------------------------------------
// CSR build: histogram -> exclusive scan -> scatter
// edge list: e < NE: src=ei[e], dst=ei[NE+e]; e >= NE: self loop src=dst=e-NE
// ----------------------------------------------------------------------------
__global__ void count_kernel(const int* __restrict__ ei, int* __restrict__ cnt)
{
  int e = blockIdx.x * blockDim.x + threadIdx.x;
  if (e < NEDGE) {
    int d = (e < NE) ? ei[NE + e] : (e - NE);
    atomicAdd(&cnt[d], 1);
  }
}

__global__ __launch_bounds__(1024) void scan_kernel(
    const int* __restrict__ cnt, int* __restrict__ offs, int* __restrict__ cursor)
{
  __shared__ int smem[1024];
  __shared__ int carry;
  int tid = threadIdx.x;
  if (tid == 0) carry = 0;
  __syncthreads();
  for (int base = 0; base < NN; base += 1024) {
    int v = (base + tid < NN) ? cnt[base + tid] : 0;
    smem[tid] = v;
    __syncthreads();
    for (int off = 1; off < 1024; off <<= 1) {
      int t = (tid >= off) ? smem[tid - off] : 0;
      __syncthreads();
      smem[tid] += t;
      __syncthreads();
    }
    int excl = smem[tid] - v + carry;
    if (base + tid < NN) { offs[base + tid] = excl; cursor[base + tid] = excl; }
    __syncthreads();
    if (tid == 0) carry += smem[1023];
    __syncthreads();
  }
  if (tid == 0) offs[NN] = NEDGE;
}

__global__ void scatter_kernel(const int* __restrict__ ei, int* __restrict__ cursor,
                               int* __restrict__ csr_src)
{
  int e = blockIdx.x * blockDim.x + threadIdx.x;
  if (e < NEDGE) {
    int s, d;
    if (e < NE) { s = ei[e]; d = ei[NE + e]; }
    else { s = e - NE; d = e - NE; }
    int p = atomicAdd(&cursor[d], 1);
    csr_src[p] = s;
  }
}

// ----------------------------------------------------------------------------
// GATv2 aggregation, one wave per destination node, online softmax, fused
// +gbias +residual +LayerNorm epilogue. Channels: lane holds c=4*lane..4*lane+3,
// head = lane/16 (16 lanes per head of 64 channels).
// ----------------------------------------------------------------------------
__global__ __launch_bounds__(256) void gat_kernel(
    const float* __restrict__ xl, const float* __restrict__ xr,
    const float* __restrict__ x_in, const float* __restrict__ att,
    const float* __restrict__ gbias, const float* __restrict__ ln_g,
    const float* __restrict__ ln_b, const int* __restrict__ offs,
    const int* __restrict__ csr_src, float* __restrict__ x_out)
{
  int wave = threadIdx.x >> 6, lane = threadIdx.x & 63;
  int node = blockIdx.x * 4 + wave;
  if (node >= NN) return;
  int c = lane << 2;
  float4 xrv = *(const float4*)(xr + (size_t)node * HID + c);
  float4 attv = *(const float4*)(att + c);

  float m = -INFINITY, l = 0.f;
  float a0 = 0.f, a1 = 0.f, a2 = 0.f, a3 = 0.f;

  int beg = offs[node], end = offs[node + 1];
  for (int e = beg; e < end; e++) {
    int s = csr_src[e];
    float4 xlv = *(const float4*)(xl + (size_t)s * HID + c);
    float e0 = xlv.x + xrv.x, e1 = xlv.y + xrv.y, e2 = xlv.z + xrv.z, e3 = xlv.w + xrv.w;
    e0 = (e0 > 0.f) ? e0 : NEG * e0;
    e1 = (e1 > 0.f) ? e1 : NEG * e1;
    e2 = (e2 > 0.f) ? e2 : NEG * e2;
    e3 = (e3 > 0.f) ? e3 : NEG * e3;
    float local = e0 * attv.x + e1 * attv.y + e2 * attv.z + e3 * attv.w;
    // reduce over the 16 lanes of this head
    local += __shfl_xor(local, 1, 16);
    local += __shfl_xor(local, 2, 16);
    local += __shfl_xor(local, 4, 16);
    local += __shfl_xor(local, 8, 16);
    float logit = local;
    float mn = fmaxf(m, logit);
    float sc = __expf(m - mn);    // m = -inf first iter -> 0
    float w  = __expf(logit - mn);
    l = l * sc + w;
    a0 = a0 * sc + w * xlv.x;
    a1 = a1 * sc + w * xlv.y;
    a2 = a2 * sc + w * xlv.z;
    a3 = a3 * sc + w * xlv.w;
    m = mn;
  }
  float inv = 1.f / l;
  float4 xv = *(const float4*)(x_in + (size_t)node * HID + c);
  float4 gb = *(const float4*)(gbias + c);
  float o0 = a0 * inv + gb.x + xv.x;
  float o1 = a1 * inv + gb.y + xv.y;
  float o2 = a2 * inv + gb.z + xv.z;
  float o3 = a3 * inv + gb.w + xv.w;
  // LayerNorm across all 256 channels (full wave)
  float s1 = o0 + o1 + o2 + o3;
  float s2 = o0 * o0 + o1 * o1 + o2 * o2 + o3 * o3;
#pragma unroll
  for (int mm = 1; mm < 64; mm <<= 1) {
    s1 += __shfl_xor(s1, mm, 64);
    s2 += __shfl_xor(s2, mm, 64);
  }
  float mu = s1 * (1.f / 256.f);
  float var = s2 * (1.f / 256.f) - mu * mu;
  float rstd = rsqrtf(var + EPSV);
  float4 gv = *(const float4*)(ln_g + c);
  float4 bv = *(const float4*)(ln_b + c);
  float4 o;
  o.x = (o0 - mu) * rstd * gv.x + bv.x;
  o.y = (o1 - mu) * rstd * gv.y + bv.y;
  o.z = (o2 - mu) * rstd * gv.z + bv.z;
  o.w = (o3 - mu) * rstd * gv.w + bv.w;
  *(float4*)(x_out + (size_t)node * HID + c) = o;
}

// ----------------------------------------------------------------------------
// Final head: out[N,3] = t1[N,256] @ W[256,3] + b. One wave per row.
// ----------------------------------------------------------------------------
__global__ __launch_bounds__(256) void head2_kernel(
    const float* __restrict__ t1, const float* __restrict__ W,
    const float* __restrict__ bias, float* __restrict__ out)
{
  int wave = threadIdx.x >> 6, lane = threadIdx.x & 63;
  int row = blockIdx.x * 4 + wave;
  if (row >= NN) return;
  int c = lane << 2;
  float4 v = *(const float4*)(t1 + (size_t)row * HID + c);
  float p0 = 0.f, p1 = 0.f, p2 = 0.f;
#pragma unroll
  for (int j = 0; j < 4; j++) {
    float vj = (&v.x)[j];
    p0 += vj * W[(c + j) * 3 + 0];
    p1 += vj * W[(c + j) * 3 + 1];
    p2 += vj * W[(c + j) * 3 + 2];
  }
#pragma unroll
  for (int mm = 1; mm < 64; mm <<= 1) {
    p0 += __shfl_xor(p0, mm, 64);
    p1 += __shfl_xor(p1, mm, 64);
    p2 += __shfl_xor(p2, mm, 64);
  }
  if (lane == 0) {
    out[(size_t)row * 3 + 0] = p0 + bias[0];
    out[(size_t)row * 3 + 1] = p1 + bias[1];
    out[(size_t)row * 3 + 2] = p2 + bias[2];
  }
}

// ----------------------------------------------------------------------------
extern "C" void kernel_launch(void* const* d_in, const int* in_sizes, int n_in,
                              void* d_out, int out_size, void* d_ws, size_t ws_size,
                              hipStream_t stream)
{
  const float* features = (const float*)d_in[0];
  const int*   ei       = (const int*)d_in[1];
  const float* proj_W   = (const float*)d_in[2];
  const float* proj_b   = (const float*)d_in[3];
  const float* n0_g     = (const float*)d_in[4];
  const float* n0_b     = (const float*)d_in[5];
  const float* Wl       = (const float*)d_in[6];
  const float* bl       = (const float*)d_in[7];
  const float* Wr       = (const float*)d_in[8];
  const float* br       = (const float*)d_in[9];
  const float* att      = (const float*)d_in[10];
  const float* gbias    = (const float*)d_in[11];
  const float* ln_g     = (const float*)d_in[12];
  const float* ln_b     = (const float*)d_in[13];
  const float* h1_W     = (const float*)d_in[14];
  const float* h1_b     = (const float*)d_in[15];
  const float* h2_W     = (const float*)d_in[16];
  const float* h2_b     = (const float*)d_in[17];
  float* out = (float*)d_out;

  char* w = (char*)d_ws;
  float* x0 = (float*)w;  w += (size_t)NN * HID * 4;
  float* x1 = (float*)w;  w += (size_t)NN * HID * 4;
  float* xl = (float*)w;  w += (size_t)NN * HID * 4;
  float* xr = (float*)w;  w += (size_t)NN * HID * 4;
  int* cnt    = (int*)w;  w += (size_t)NN * 4;
  int* offs   = (int*)w;  w += (size_t)(NN + 1) * 4;
  int* cursor = (int*)w;  w += (size_t)NN * 4;
  int* csr    = (int*)w;  w += (size_t)NEDGE * 4;

  // ---- CSR build (edges constant across hops)
  hipMemsetAsync(cnt, 0, (size_t)NN * 4, stream);
  count_kernel<<<(NEDGE + 255) / 256, 256, 0, stream>>>(ei, cnt);
  scan_kernel<<<1, 1024, 0, stream>>>(cnt, offs, cursor);
  scatter_kernel<<<(NEDGE + 255) / 256, 256, 0, stream>>>(ei, cursor, csr);

  dim3 g64(HID / 64, (NN + 63) / 64);

  // ---- input projection + LN
  gemm_bias_kernel<<<g64, 256, 0, stream>>>(features, proj_W, proj_b, xl, NN, INDIM, HID, 0);
  ln4_kernel<<<(NN + 3) / 4, 256, 0, stream>>>(xl, n0_g, n0_b, x0, NN);

  // ---- 3 GAT hops
  float* xcur = x0;
  float* xnxt = x1;
  for (int h = 0; h < 3; h++) {
    gemm_bias_kernel<<<g64, 256, 0, stream>>>(xcur, Wl + (size_t)h * HID * HID, bl + h * HID, xl, NN, HID, HID, 0);
    gemm_bias_kernel<<<g64, 256, 0, stream>>>(xcur, Wr + (size_t)h * HID * HID, br + h * HID, xr, NN, HID, HID, 0);
    gat_kernel<<<(NN + 3) / 4, 256, 0, stream>>>(
        xl, xr, xcur, att + h * HID, gbias + h * HID,
        ln_g + h * HID, ln_b + h * HID, offs, csr, xnxt);
    float* t = xcur; xcur = xnxt; xnxt = t;
  }

  // ---- head
  gemm_bias_kernel<<<g64, 256, 0, stream>>>(xcur, h1_W, h1_b, xl, NN, HID, HID, 1);
  head2_kernel<<<(NN + 3) / 4, 256, 0, stream>>>(xl, h2_W, h2_b, out);
}

// Round 2
// 660.655 us; speedup vs baseline: 1.4429x; 1.4429x over previous
//
#include <hip/hip_runtime.h>
#include <hip/hip_bf16.h>
#include <math.h>

#define NN 20000
#define MPAD 20096            // 157 * 128
#define INDIM 1536
#define HID 256
#define NE 320000
#define NEDGE (NE + NN)
#define EPSV 1e-5f
#define NEG 0.2f

typedef unsigned short ushort_b;
typedef unsigned int uint32;
typedef __bf16 bf16x8 __attribute__((ext_vector_type(8)));
typedef float f32x4 __attribute__((ext_vector_type(4)));

#define AS1(p) ((const __attribute__((address_space(1))) void*)(p))
#define AS3(p) ((__attribute__((address_space(3))) void*)(p))

__device__ inline ushort_b f2bf(float x) {
  union { float f; uint32 u; } v; v.f = x;
  uint32 r = v.u + 0x7FFFu + ((v.u >> 16) & 1u);   // RNE
  return (ushort_b)(r >> 16);
}
__device__ inline float bf2f(ushort_b h) {
  union { uint32 u; float f; } v; v.u = ((uint32)h) << 16;
  return v.f;
}
__device__ inline float4 ldbf4(const ushort_b* p) {
  ushort4 u = *(const ushort4*)p;
  float4 f;
  f.x = bf2f(u.x); f.y = bf2f(u.y); f.z = bf2f(u.z); f.w = bf2f(u.w);
  return f;
}

// ----------------------------------------------------------------------------
// bf16 MFMA GEMM: C[M,256] = A[M,K] @ B[K,256] + bias
//   Bt is B transposed [256][K] bf16 (so B-fragments are contiguous).
//   BM=128 BN=128 BK=32, 256 threads = 4 waves (2x2 of 64x64), 16x16x32 MFMA.
//   AFP32: A is fp32, staged with in-register cvt (guarded rows); else A is
//          bf16 padded to MPAD rows, staged via global_load_lds width 16.
//   OUTMODE: 0 = fp32, 1 = fp32 + exact GELU, 2 = bf16.
//   grid.z selects (Bt0,bias0,C0) / (Bt1,bias1,C1) - dual-B launch shares A.
// ----------------------------------------------------------------------------
template<int AFP32, int OUTMODE>
__global__ __launch_bounds__(256) void gemm_mfma(
    const void* __restrict__ Av,
    const ushort_b* __restrict__ Bt0, const ushort_b* __restrict__ Bt1,
    const float* __restrict__ bias0, const float* __restrict__ bias1,
    void* __restrict__ C0, void* __restrict__ C1,
    int Mstore, int K)
{
  __shared__ ushort_b As[128 * 32];
  __shared__ ushort_b Bs[128 * 32];
  const ushort_b* Bt = blockIdx.z ? Bt1 : Bt0;
  const float* bias  = blockIdx.z ? bias1 : bias0;
  void* Cv           = blockIdx.z ? C1 : C0;

  int tid = threadIdx.x;
  int wave = tid >> 6, lane = tid & 63;
  int r0 = blockIdx.y * 128;
  int c0 = blockIdx.x * 128;
  int wm = (wave >> 1) << 6, wn = (wave & 1) << 6;
  int mrow = lane & 15, quad = lane >> 4;

  f32x4 acc[4][4] = {};

  for (int k0 = 0; k0 < K; k0 += 32) {
    // ---- stage B^T tile [128 rows x 32 k] via global_load_lds (16B/lane)
#pragma unroll
    for (int it = 0; it < 2; it++) {
      int off = (wave << 10) + (it << 12) + (lane << 4);   // byte offset in tile
      int row = off >> 6;
      int colb = off & 63;
      const char* gB = (const char*)Bt + ((size_t)(c0 + row) * K + k0) * 2 + colb;
      __builtin_amdgcn_global_load_lds(AS1(gB), AS3((char*)Bs + off), 16, 0, 0);
    }
    // ---- stage A tile
    if (AFP32) {
      const float* Af = (const float*)Av;
#pragma unroll
      for (int p = 0; p < 4; p++) {
        int off4 = (p << 8) + tid;          // float4 index, 8 per row
        int row = off4 >> 3, col4 = off4 & 7;
        float4 av = make_float4(0.f, 0.f, 0.f, 0.f);
        int grow = r0 + row;
        if (grow < Mstore) av = *(const float4*)(Af + (size_t)grow * K + k0 + (col4 << 2));
        uint2 u;
        u.x = (uint32)f2bf(av.x) | ((uint32)f2bf(av.y) << 16);
        u.y = (uint32)f2bf(av.z) | ((uint32)f2bf(av.w) << 16);
        *(uint2*)(As + (row << 5) + (col4 << 2)) = u;
      }
    } else {
      const ushort_b* Ab = (const ushort_b*)Av;   // padded to MPAD rows
#pragma unroll
      for (int it = 0; it < 2; it++) {
        int off = (wave << 10) + (it << 12) + (lane << 4);
        int row = off >> 6;
        int colb = off & 63;
        const char* gA = (const char*)Ab + ((size_t)(r0 + row) * K + k0) * 2 + colb;
        __builtin_amdgcn_global_load_lds(AS1(gA), AS3((char*)As + off), 16, 0, 0);
      }
    }
    __syncthreads();

    // ---- fragments + 16 MFMAs
    bf16x8 af[4], bfr[4];
#pragma unroll
    for (int t = 0; t < 4; t++) {
      af[t]  = *(const bf16x8*)(As + ((wm + (t << 4) + mrow) << 5) + (quad << 3));
      bfr[t] = *(const bf16x8*)(Bs + ((wn + (t << 4) + mrow) << 5) + (quad << 3));
    }
#pragma unroll
    for (int mt = 0; mt < 4; mt++)
#pragma unroll
      for (int nt = 0; nt < 4; nt++)
        acc[mt][nt] = __builtin_amdgcn_mfma_f32_16x16x32_bf16(af[mt], bfr[nt], acc[mt][nt], 0, 0, 0);
    __syncthreads();
  }

  // ---- epilogue: D[row=quad*4+r][col=lane&15] per 16x16 tile
#pragma unroll
  for (int nt = 0; nt < 4; nt++) {
    int col = c0 + wn + (nt << 4) + mrow;
    float bb = bias[col];
#pragma unroll
    for (int mt = 0; mt < 4; mt++) {
#pragma unroll
      for (int r = 0; r < 4; r++) {
        int row = r0 + wm + (mt << 4) + (quad << 2) + r;
        if (row < Mstore) {
          float v = acc[mt][nt][r] + bb;
          if (OUTMODE == 1) v = 0.5f * v * (1.f + erff(v * 0.70710678118654752f));
          if (OUTMODE == 2) ((ushort_b*)Cv)[(size_t)row * 256 + col] = f2bf(v);
          else              ((float*)Cv)[(size_t)row * 256 + col] = v;
        }
      }
    }
  }
}

// ----------------------------------------------------------------------------
// transpose + cast: in[R][C] fp32 -> out[C][R] bf16 (R,C multiples of 32)
// ----------------------------------------------------------------------------
__global__ __launch_bounds__(256) void transpose_cast(
    const float* __restrict__ in, ushort_b* __restrict__ out, int R, int C)
{
  __shared__ float t[32][33];
  int bx = blockIdx.x * 32;   // C
  int by = blockIdx.y * 32;   // R
  for (int i = threadIdx.y; i < 32; i += 8)
    t[i][threadIdx.x] = in[(size_t)(by + i) * C + bx + threadIdx.x];
  __syncthreads();
  for (int i = threadIdx.y; i < 32; i += 8)
    out[(size_t)(bx + i) * R + by + threadIdx.x] = f2bf(t[threadIdx.x][i]);
}

// ----------------------------------------------------------------------------
// LayerNorm (rows of 256), writes fp32 + bf16 copies. One wave per row.
// ----------------------------------------------------------------------------
__global__ __launch_bounds__(256) void ln4_kernel(
    const float* __restrict__ in, const float* __restrict__ g,
    const float* __restrict__ b, float* __restrict__ out,
    ushort_b* __restrict__ bf_out, int n)
{
  int wave = threadIdx.x >> 6, lane = threadIdx.x & 63;
  int row = blockIdx.x * 4 + wave;
  if (row >= n) return;
  int c = lane << 2;
  float4 v = *(const float4*)(in + (size_t)row * HID + c);
  float s1 = v.x + v.y + v.z + v.w;
  float s2 = v.x * v.x + v.y * v.y + v.z * v.z + v.w * v.w;
#pragma unroll
  for (int m = 1; m < 64; m <<= 1) {
    s1 += __shfl_xor(s1, m, 64);
    s2 += __shfl_xor(s2, m, 64);
  }
  float mu = s1 * (1.f / 256.f);
  float var = s2 * (1.f / 256.f) - mu * mu;
  float rstd = rsqrtf(var + EPSV);
  float4 gv = *(const float4*)(g + c);
  float4 bv = *(const float4*)(b + c);
  float4 o;
  o.x = (v.x - mu) * rstd * gv.x + bv.x;
  o.y = (v.y - mu) * rstd * gv.y + bv.y;
  o.z = (v.z - mu) * rstd * gv.z + bv.z;
  o.w = (v.w - mu) * rstd * gv.w + bv.w;
  *(float4*)(out + (size_t)row * HID + c) = o;
  ushort4 ub;
  ub.x = f2bf(o.x); ub.y = f2bf(o.y); ub.z = f2bf(o.z); ub.w = f2bf(o.w);
  *(ushort4*)(bf_out + (size_t)row * HID + c) = ub;
}

// ----------------------------------------------------------------------------
// CSR build
// ----------------------------------------------------------------------------
__global__ void count_kernel(const int* __restrict__ ei, int* __restrict__ cnt)
{
  int e = blockIdx.x * blockDim.x + threadIdx.x;
  if (e < NEDGE) {
    int d = (e < NE) ? ei[NE + e] : (e - NE);
    atomicAdd(&cnt[d], 1);
  }
}

__global__ __launch_bounds__(1024) void scan_kernel(
    const int* __restrict__ cnt, int* __restrict__ offs, int* __restrict__ cursor)
{
  __shared__ int smem[1024];
  __shared__ int carry;
  int tid = threadIdx.x;
  if (tid == 0) carry = 0;
  __syncthreads();
  for (int base = 0; base < NN; base += 1024) {
    int v = (base + tid < NN) ? cnt[base + tid] : 0;
    smem[tid] = v;
    __syncthreads();
    for (int off = 1; off < 1024; off <<= 1) {
      int t = (tid >= off) ? smem[tid - off] : 0;
      __syncthreads();
      smem[tid] += t;
      __syncthreads();
    }
    int excl = smem[tid] - v + carry;
    if (base + tid < NN) { offs[base + tid] = excl; cursor[base + tid] = excl; }
    __syncthreads();
    if (tid == 0) carry += smem[1023];
    __syncthreads();
  }
  if (tid == 0) offs[NN] = NEDGE;
}

__global__ void scatter_kernel(const int* __restrict__ ei, int* __restrict__ cursor,
                               int* __restrict__ csr_src)
{
  int e = blockIdx.x * blockDim.x + threadIdx.x;
  if (e < NEDGE) {
    int s, d;
    if (e < NE) { s = ei[e]; d = ei[NE + e]; }
    else { s = e - NE; d = e - NE; }
    int p = atomicAdd(&cursor[d], 1);
    csr_src[p] = s;
  }
}

// ----------------------------------------------------------------------------
// GATv2 aggregation: one wave per dst node, 2-way-ILP online softmax,
// bf16 xl/xr inputs, fused +gbias +residual +LN, writes fp32 + bf16.
// ----------------------------------------------------------------------------
#define UPD(mS, lS, q0, q1, q2, q3, lg, xv) {      \
    float mn = fmaxf(mS, lg);                       \
    float sc = __expf(mS - mn);                     \
    float w  = __expf(lg - mn);                     \
    lS = lS * sc + w;                               \
    q0 = q0 * sc + w * xv.x;                        \
    q1 = q1 * sc + w * xv.y;                        \
    q2 = q2 * sc + w * xv.z;                        \
    q3 = q3 * sc + w * xv.w;                        \
    mS = mn; }

__device__ inline float edge_logit(float4 xv, float4 xrv, float4 attv) {
  float e0 = xv.x + xrv.x, e1 = xv.y + xrv.y, e2 = xv.z + xrv.z, e3 = xv.w + xrv.w;
  e0 = (e0 > 0.f) ? e0 : NEG * e0;
  e1 = (e1 > 0.f) ? e1 : NEG * e1;
  e2 = (e2 > 0.f) ? e2 : NEG * e2;
  e3 = (e3 > 0.f) ? e3 : NEG * e3;
  float lc = e0 * attv.x + e1 * attv.y + e2 * attv.z + e3 * attv.w;
  lc += __shfl_xor(lc, 1, 16);
  lc += __shfl_xor(lc, 2, 16);
  lc += __shfl_xor(lc, 4, 16);
  lc += __shfl_xor(lc, 8, 16);
  return lc;
}

__global__ __launch_bounds__(256) void gat_kernel(
    const ushort_b* __restrict__ xl, const ushort_b* __restrict__ xr,
    const float* __restrict__ x_in, const float* __restrict__ att,
    const float* __restrict__ gbias, const float* __restrict__ ln_g,
    const float* __restrict__ ln_b, const int* __restrict__ offs,
    const int* __restrict__ csr_src, float* __restrict__ x_out,
    ushort_b* __restrict__ xb_out)
{
  int wave = threadIdx.x >> 6, lane = threadIdx.x & 63;
  int node = blockIdx.x * 4 + wave;
  if (node >= NN) return;
  int c = lane << 2;
  float4 xrv = ldbf4(xr + (size_t)node * HID + c);
  float4 attv = *(const float4*)(att + c);

  float m1 = -INFINITY, l1 = 0.f, p10 = 0.f, p11 = 0.f, p12 = 0.f, p13 = 0.f;
  float m2 = -INFINITY, l2 = 0.f, p20 = 0.f, p21 = 0.f, p22 = 0.f, p23 = 0.f;

  int e = offs[node], end = offs[node + 1];
  for (; e + 1 < end; e += 2) {
    int s1 = csr_src[e], s2 = csr_src[e + 1];
    float4 xa = ldbf4(xl + (size_t)s1 * HID + c);
    float4 xb = ldbf4(xl + (size_t)s2 * HID + c);
    float la = edge_logit(xa, xrv, attv);
    float lb = edge_logit(xb, xrv, attv);
    UPD(m1, l1, p10, p11, p12, p13, la, xa);
    UPD(m2, l2, p20, p21, p22, p23, lb, xb);
  }
  if (e < end) {
    int s1 = csr_src[e];
    float4 xa = ldbf4(xl + (size_t)s1 * HID + c);
    float la = edge_logit(xa, xrv, attv);
    UPD(m1, l1, p10, p11, p12, p13, la, xa);
  }
  // merge state2 into state1 (state1 always non-empty: degree >= 1 via self-loop)
  float mm = fmaxf(m1, m2);
  float sA = __expf(m1 - mm), sB = (m2 == -INFINITY) ? 0.f : __expf(m2 - mm);
  float l = l1 * sA + l2 * sB;
  float inv = 1.f / l;
  float a0 = (p10 * sA + p20 * sB) * inv;
  float a1 = (p11 * sA + p21 * sB) * inv;
  float a2 = (p12 * sA + p22 * sB) * inv;
  float a3 = (p13 * sA + p23 * sB) * inv;

  float4 xv = *(const float4*)(x_in + (size_t)node * HID + c);
  float4 gb = *(const float4*)(gbias + c);
  float o0 = a0 + gb.x + xv.x;
  float o1 = a1 + gb.y + xv.y;
  float o2 = a2 + gb.z + xv.z;
  float o3 = a3 + gb.w + xv.w;
  float s1s = o0 + o1 + o2 + o3;
  float s2s = o0 * o0 + o1 * o1 + o2 * o2 + o3 * o3;
#pragma unroll
  for (int mmk = 1; mmk < 64; mmk <<= 1) {
    s1s += __shfl_xor(s1s, mmk, 64);
    s2s += __shfl_xor(s2s, mmk, 64);
  }
  float mu = s1s * (1.f / 256.f);
  float var = s2s * (1.f / 256.f) - mu * mu;
  float rstd = rsqrtf(var + EPSV);
  float4 gv = *(const float4*)(ln_g + c);
  float4 bv = *(const float4*)(ln_b + c);
  float4 o;
  o.x = (o0 - mu) * rstd * gv.x + bv.x;
  o.y = (o1 - mu) * rstd * gv.y + bv.y;
  o.z = (o2 - mu) * rstd * gv.z + bv.z;
  o.w = (o3 - mu) * rstd * gv.w + bv.w;
  *(float4*)(x_out + (size_t)node * HID + c) = o;
  ushort4 ub;
  ub.x = f2bf(o.x); ub.y = f2bf(o.y); ub.z = f2bf(o.z); ub.w = f2bf(o.w);
  *(ushort4*)(xb_out + (size_t)node * HID + c) = ub;
}

// ----------------------------------------------------------------------------
// Final head: out[N,3] = t1[N,256] @ W[256,3] + b. One wave per row.
// ----------------------------------------------------------------------------
__global__ __launch_bounds__(256) void head2_kernel(
    const float* __restrict__ t1, const float* __restrict__ W,
    const float* __restrict__ bias, float* __restrict__ out)
{
  int wave = threadIdx.x >> 6, lane = threadIdx.x & 63;
  int row = blockIdx.x * 4 + wave;
  if (row >= NN) return;
  int c = lane << 2;
  float4 v = *(const float4*)(t1 + (size_t)row * HID + c);
  float p0 = 0.f, p1 = 0.f, p2 = 0.f;
#pragma unroll
  for (int j = 0; j < 4; j++) {
    float vj = (&v.x)[j];
    p0 += vj * W[(c + j) * 3 + 0];
    p1 += vj * W[(c + j) * 3 + 1];
    p2 += vj * W[(c + j) * 3 + 2];
  }
#pragma unroll
  for (int mm = 1; mm < 64; mm <<= 1) {
    p0 += __shfl_xor(p0, mm, 64);
    p1 += __shfl_xor(p1, mm, 64);
    p2 += __shfl_xor(p2, mm, 64);
  }
  if (lane == 0) {
    out[(size_t)row * 3 + 0] = p0 + bias[0];
    out[(size_t)row * 3 + 1] = p1 + bias[1];
    out[(size_t)row * 3 + 2] = p2 + bias[2];
  }
}

// ----------------------------------------------------------------------------
extern "C" void kernel_launch(void* const* d_in, const int* in_sizes, int n_in,
                              void* d_out, int out_size, void* d_ws, size_t ws_size,
                              hipStream_t stream)
{
  const float* features = (const float*)d_in[0];
  const int*   ei       = (const int*)d_in[1];
  const float* proj_W   = (const float*)d_in[2];
  const float* proj_b   = (const float*)d_in[3];
  const float* n0_g     = (const float*)d_in[4];
  const float* n0_b     = (const float*)d_in[5];
  const float* Wl       = (const float*)d_in[6];
  const float* bl       = (const float*)d_in[7];
  const float* Wr       = (const float*)d_in[8];
  const float* br       = (const float*)d_in[9];
  const float* att      = (const float*)d_in[10];
  const float* gbias    = (const float*)d_in[11];
  const float* ln_g     = (const float*)d_in[12];
  const float* ln_b     = (const float*)d_in[13];
  const float* h1_W     = (const float*)d_in[14];
  const float* h1_b     = (const float*)d_in[15];
  const float* h2_W     = (const float*)d_in[16];
  const float* h2_b     = (const float*)d_in[17];
  float* out = (float*)d_out;

  char* w = (char*)d_ws;
  float*    x0   = (float*)w;    w += (size_t)NN * HID * 4;
  float*    x1   = (float*)w;    w += (size_t)NN * HID * 4;
  ushort_b* xlb  = (ushort_b*)w; w += (size_t)NN * HID * 2;
  ushort_b* xrb  = (ushort_b*)w; w += (size_t)NN * HID * 2;
  ushort_b* xb   = (ushort_b*)w; w += (size_t)MPAD * HID * 2;
  ushort_b* wtp  = (ushort_b*)w; w += (size_t)HID * INDIM * 2;   // proj_W^T
  ushort_b* wtl  = (ushort_b*)w; w += (size_t)3 * HID * HID * 2; // Wl^T per hop
  ushort_b* wtr  = (ushort_b*)w; w += (size_t)3 * HID * HID * 2;
  ushort_b* wth1 = (ushort_b*)w; w += (size_t)HID * HID * 2;
  int* cnt    = (int*)w;  w += (size_t)NN * 4;
  int* offs   = (int*)w;  w += (size_t)(NN + 1) * 4;
  int* cursor = (int*)w;  w += (size_t)NN * 4;
  int* csr    = (int*)w;  w += (size_t)NEDGE * 4;

  // ---- CSR build + pad-row zeroing
  hipMemsetAsync(cnt, 0, (size_t)NN * 4, stream);
  hipMemsetAsync(xb + (size_t)NN * HID, 0, (size_t)(MPAD - NN) * HID * 2, stream);
  count_kernel<<<(NEDGE + 255) / 256, 256, 0, stream>>>(ei, cnt);
  scan_kernel<<<1, 1024, 0, stream>>>(cnt, offs, cursor);
  scatter_kernel<<<(NEDGE + 255) / 256, 256, 0, stream>>>(ei, cursor, csr);

  // ---- weight transposes (fp32 -> bf16 B^T)
  transpose_cast<<<dim3(HID / 32, INDIM / 32), dim3(32, 8), 0, stream>>>(proj_W, wtp, INDIM, HID);
  for (int h = 0; h < 3; h++) {
    transpose_cast<<<dim3(HID / 32, HID / 32), dim3(32, 8), 0, stream>>>(
        Wl + (size_t)h * HID * HID, wtl + (size_t)h * HID * HID, HID, HID);
    transpose_cast<<<dim3(HID / 32, HID / 32), dim3(32, 8), 0, stream>>>(
        Wr + (size_t)h * HID * HID, wtr + (size_t)h * HID * HID, HID, HID);
  }
  transpose_cast<<<dim3(HID / 32, HID / 32), dim3(32, 8), 0, stream>>>(h1_W, wth1, HID, HID);

  dim3 gproj(2, MPAD / 128, 1);
  dim3 ghop(2, MPAD / 128, 2);

  // ---- input projection (fp32 A) + LN
  gemm_mfma<1, 0><<<gproj, 256, 0, stream>>>(features, wtp, wtp, proj_b, proj_b,
                                             x1, x1, NN, INDIM);
  ln4_kernel<<<(NN + 3) / 4, 256, 0, stream>>>(x1, n0_g, n0_b, x0, xb, NN);

  // ---- 3 GAT hops
  float* xcur = x0;
  float* xnxt = x1;
  for (int h = 0; h < 3; h++) {
    gemm_mfma<0, 2><<<ghop, 256, 0, stream>>>(
        xb, wtl + (size_t)h * HID * HID, wtr + (size_t)h * HID * HID,
        bl + h * HID, br + h * HID, xlb, xrb, NN, HID);
    gat_kernel<<<(NN + 3) / 4, 256, 0, stream>>>(
        xlb, xrb, xcur, att + h * HID, gbias + h * HID,
        ln_g + h * HID, ln_b + h * HID, offs, csr, xnxt, xb);
    float* t = xcur; xcur = xnxt; xnxt = t;
  }

  // ---- head: h1 (GELU) then 256x3
  gemm_mfma<0, 1><<<gproj, 256, 0, stream>>>(xb, wth1, wth1, h1_b, h1_b,
                                             xnxt, xnxt, NN, HID);
  head2_kernel<<<(NN + 3) / 4, 256, 0, stream>>>(xnxt, h2_W, h2_b, out);
}